// Round 24
// baseline (278.408 us; speedup 1.0000x reference)
//
#include <hip/hip_runtime.h>
#include <hip/hip_bf16.h>

#define HH 1024
#define BB 32
#define TT 2048

typedef __attribute__((ext_vector_type(8))) short bf16x8;
typedef __attribute__((ext_vector_type(4))) float f32x4;

static __device__ __forceinline__ unsigned short f2bf(float f) {
    unsigned int u = __float_as_uint(f);
    unsigned int r = u + 0x7fffu + ((u >> 16) & 1u);
    return (unsigned short)(r >> 16);
}
static __device__ __forceinline__ float bf2f(unsigned short u) {
    return __uint_as_float(((unsigned int)u) << 16);
}
// pack 2 f32 -> 2 bf16 (RNE), single HW instruction
static __device__ __forceinline__ unsigned int cvt_pk_bf16(float lo, float hi) {
    unsigned int d;
    asm volatile("v_cvt_pk_bf16_f32 %0, %1, %2" : "=v"(d) : "v"(lo), "v"(hi));
    return d;
}
// tanh(x) = 1 - 2/(1+e^{2x}); exact at limits, err ~1e-6
static __device__ __forceinline__ float fast_tanh(float x) {
    float e = __expf(2.0f * x);
    return 1.0f - 2.0f / (e + 1.0f);
}

#define GLOAD_LDS16(gp, lp) \
    __builtin_amdgcn_global_load_lds( \
        (const __attribute__((address_space(1))) void*)(gp), \
        (__attribute__((address_space(3))) void*)(lp), 16, 0, 0)

// ---- convert Wa_w (fp32 [H][H]) to bf16 in ws ----
__global__ void k_convW(const float* __restrict__ W, unsigned short* __restrict__ Wb) {
    int i = blockIdx.x * 256 + threadIdx.x;
    float4 v = ((const float4*)W)[i];
    ushort4 o;
    o.x = f2bf(v.x); o.y = f2bf(v.y); o.z = f2bf(v.z); o.w = f2bf(v.w);
    ((ushort4*)Wb)[i] = o;
}

// ---- dec_proj[b][o] = dot(dec[b,:], Ua_w[o,:]) + Ua_b[o] + Wa_b[o] ----
__global__ void k_decproj(const float* __restrict__ dec, const float* __restrict__ Ua,
                          const float* __restrict__ Uab, const float* __restrict__ Wab,
                          float* __restrict__ dp) {
    int gtid = blockIdx.x * 256 + threadIdx.x;   // 32768
    int b = gtid >> 10, o = gtid & 1023;
    const float4* d4 = (const float4*)(dec + (long)b * HH);
    const float4* u4 = (const float4*)(Ua + (long)o * HH);
    float acc = 0.f;
    for (int k = 0; k < HH / 4; ++k) {
        float4 a = d4[k], w = u4[k];
        acc += a.x * w.x + a.y * w.y + a.z * w.z + a.w * w.w;
    }
    dp[gtid] = acc + Uab[o] + Wab[o];
}

// === FAST PATH: r23 kernel + encb side-product ===
// A (fp32 enc): tile-deep reg-staged pipeline (r23, proven 211us). The cvt
// results additionally stream to encb (bf16 copy of enc) for k_context_bf:
// block nt stores k-tiles with k&3==nt (load-balanced, each tile written
// exactly once). Stores slot between cvt and A(t+2) loads; vmcnt(8) then
// waits {B gloads + stores} while A loads stay in flight.
template<int WRITE_ENC>
__global__ __launch_bounds__(512) void k_score_bf(
        const float* __restrict__ enc, const unsigned short* __restrict__ Wb,
        const float* __restrict__ dp, const float* __restrict__ vw,
        float* __restrict__ scores, unsigned short* __restrict__ encb) {
    __shared__ __align__(16) unsigned short As[2][256 * 64];
    __shared__ __align__(16) unsigned short Bs[2][256 * 64];
    int bid = blockIdx.x;            // 1024 blocks = 256 mt x 4 nt
    int xcd = bid & 7;
    int ord = bid >> 3;              // 0..127 per XCD
    int nt = ord & 3;                // XCD walks nt 0..3 (A-panel L2-reuse)
    int mt = (ord >> 2) * 8 + xcd;   // 0..255
    long m0 = (long)mt * 256;
    int o0b = nt * 256;
    int tid = threadIdx.x;
    int lane = tid & 63, wid = tid >> 6;      // 8 waves
    int wm = wid >> 2, wn = wid & 3;          // 2 x 4; wave tile 128r x 64c
    int r = lane & 15, g = lane >> 4;

    f32x4 acc[8][4];
    #pragma unroll
    for (int i = 0; i < 8; ++i)
        #pragma unroll
        for (int j = 0; j < 4; ++j) acc[i][j] = (f32x4){0.f, 0.f, 0.f, 0.f};

    int srow = tid >> 3;
    int acol = (tid & 7) * 8;
    int awu = (tid & 7) ^ (srow & 7);
    const float* aSrcF = enc + (m0 + srow) * HH + acol;
    const unsigned short* bSrc = Wb + (long)(o0b + srow) * HH + awu * 8;
    unsigned short* eDst = WRITE_ENC ? encb + (m0 + srow) * HH + acol : nullptr;
    int ldso = wid * 512;
    int rx = r & 7;
    int u0 = (g ^ rx) * 8;
    int u1 = ((4 + g) ^ rx) * 8;
    int aw0 = srow * 64 + awu * 8;   // + q*4096 per pass (shorts)

    float4 ar[8];                    // A prefetch regs (one tile in flight)

    // prologue: A(0) direct (load+cvt+write[+store]), B(0) gloads, A(1) issued
    {
        float4 a0[8];
        #pragma unroll
        for (int q = 0; q < 4; ++q) {
            a0[2 * q]     = *(const float4*)(aSrcF + (long)64 * q * HH);
            a0[2 * q + 1] = *(const float4*)(aSrcF + (long)64 * q * HH + 4);
            GLOAD_LDS16(bSrc + (long)q * 64 * HH, &Bs[0][ldso + q * 4096]);
        }
        uint4 wv[4];
        #pragma unroll
        for (int q = 0; q < 4; ++q) {
            wv[q].x = cvt_pk_bf16(a0[2 * q].x, a0[2 * q].y);
            wv[q].y = cvt_pk_bf16(a0[2 * q].z, a0[2 * q].w);
            wv[q].z = cvt_pk_bf16(a0[2 * q + 1].x, a0[2 * q + 1].y);
            wv[q].w = cvt_pk_bf16(a0[2 * q + 1].z, a0[2 * q + 1].w);
            *(uint4*)(&As[0][aw0 + q * 4096]) = wv[q];
        }
        if (WRITE_ENC && nt == 0) {          // store k-tile 0
            #pragma unroll
            for (int q = 0; q < 4; ++q)
                *(uint4*)(eDst + (long)64 * q * HH) = wv[q];
        }
        #pragma unroll
        for (int q = 0; q < 4; ++q) {        // A(1): in flight across barrier
            ar[2 * q]     = *(const float4*)(aSrcF + (long)64 * q * HH + 64);
            ar[2 * q + 1] = *(const float4*)(aSrcF + (long)64 * q * HH + 64 + 4);
        }
        asm volatile("s_waitcnt vmcnt(8)" ::: "memory");   // B(0)+stores done
        asm volatile("s_waitcnt lgkmcnt(0)" ::: "memory"); // A(0) writes done
        __builtin_amdgcn_s_barrier();
        __builtin_amdgcn_sched_barrier(0);
    }

    #pragma unroll 1
    for (int t = 0; t < 16; ++t) {
        int bi = t & 1, pi = bi ^ 1;
        int kc2 = (t + 1) * 64;
        bool pre = (t < 15);

        // B fragments for the whole tile
        bf16x8 bfr[4][2];
        #pragma unroll
        for (int ni = 0; ni < 4; ++ni) {
            int rowb = (wn * 64 + ni * 16 + r) * 64;
            bfr[ni][0] = *(const bf16x8*)(&Bs[bi][rowb + u0]);
            bfr[ni][1] = *(const bf16x8*)(&Bs[bi][rowb + u1]);
        }
        // quad 0 A reads (mi = 0,1)
        bf16x8 aq[2][2][2];
        #pragma unroll
        for (int q = 0; q < 2; ++q) {
            int rowa = (wm * 128 + q * 16 + r) * 64;
            aq[0][q][0] = *(const bf16x8*)(&As[bi][rowa + u0]);
            aq[0][q][1] = *(const bf16x8*)(&As[bi][rowa + u1]);
        }

        #pragma unroll
        for (int p = 0; p < 4; ++p) {
            if (pre && p == 0) {
                GLOAD_LDS16(bSrc + kc2 + (long)0 * 64 * HH, &Bs[pi][ldso + 0 * 4096]);
                GLOAD_LDS16(bSrc + kc2 + (long)1 * 64 * HH, &Bs[pi][ldso + 1 * 4096]);
            }
            if (pre && p == 1) {
                GLOAD_LDS16(bSrc + kc2 + (long)2 * 64 * HH, &Bs[pi][ldso + 2 * 4096]);
                GLOAD_LDS16(bSrc + kc2 + (long)3 * 64 * HH, &Bs[pi][ldso + 3 * 4096]);
            }
            if (p < 3) {
                #pragma unroll
                for (int q = 0; q < 2; ++q) {
                    int rowa = (wm * 128 + (2 * (p + 1) + q) * 16 + r) * 64;
                    aq[(p + 1) & 1][q][0] = *(const bf16x8*)(&As[bi][rowa + u0]);
                    aq[(p + 1) & 1][q][1] = *(const bf16x8*)(&As[bi][rowa + u1]);
                }
            }
            __builtin_amdgcn_s_setprio(1);
            #pragma unroll
            for (int q = 0; q < 2; ++q) {
                int mi = 2 * p + q;
                #pragma unroll
                for (int ni = 0; ni < 4; ++ni) {
                    acc[mi][ni] = __builtin_amdgcn_mfma_f32_16x16x32_bf16(
                        aq[p & 1][q][0], bfr[ni][0], acc[mi][ni], 0, 0, 0);
                    acc[mi][ni] = __builtin_amdgcn_mfma_f32_16x16x32_bf16(
                        aq[p & 1][q][1], bfr[ni][1], acc[mi][ni], 0, 0, 0);
                }
            }
            __builtin_amdgcn_s_setprio(0);
        }

        // tile end: convert A(t+1) (loaded one tile ago), LDS-write, and
        // (balanced across nt) stream the bf16 tile to encb
        if (pre) {
            uint4 wv[4];
            #pragma unroll
            for (int q = 0; q < 4; ++q) {
                wv[q].x = cvt_pk_bf16(ar[2 * q].x, ar[2 * q].y);
                wv[q].y = cvt_pk_bf16(ar[2 * q].z, ar[2 * q].w);
                wv[q].z = cvt_pk_bf16(ar[2 * q + 1].x, ar[2 * q + 1].y);
                wv[q].w = cvt_pk_bf16(ar[2 * q + 1].z, ar[2 * q + 1].w);
                *(uint4*)(&As[pi][aw0 + q * 4096]) = wv[q];
            }
            if (WRITE_ENC && ((t + 1) & 3) == nt) {   // store k-tile t+1
                #pragma unroll
                for (int q = 0; q < 4; ++q)
                    *(uint4*)(eDst + (long)64 * q * HH + kc2) = wv[q];
            }
        }
        if (t < 14) {
            int kc3 = (t + 2) * 64;             // A(t+2): issue BEFORE barrier
            #pragma unroll
            for (int q = 0; q < 4; ++q) {
                ar[2 * q]     = *(const float4*)(aSrcF + (long)64 * q * HH + kc3);
                ar[2 * q + 1] = *(const float4*)(aSrcF + (long)64 * q * HH + kc3 + 4);
            }
            asm volatile("s_waitcnt vmcnt(8)" ::: "memory");   // B(t+1)+stores
        } else if (t == 14) {
            asm volatile("s_waitcnt vmcnt(0)" ::: "memory");   // B(15) done
        }
        if (pre) {
            asm volatile("s_waitcnt lgkmcnt(0)" ::: "memory"); // A writes done
            __builtin_amdgcn_s_barrier();
            __builtin_amdgcn_sched_barrier(0);
        }
    }

    // epilogue: scores[m] += sum_o tanh(acc + dp[b][o]) * v[o]
    int bb = (int)(m0 >> 11);        // 256 | 2048 -> single batch per tile
    float vv[4], dpv[4];
    #pragma unroll
    for (int ni = 0; ni < 4; ++ni) {
        int o = o0b + wn * 64 + ni * 16 + r;
        vv[ni] = vw[o];
        dpv[ni] = dp[bb * HH + o];
    }
    #pragma unroll
    for (int mi = 0; mi < 8; ++mi) {
        float vp[4] = {0.f, 0.f, 0.f, 0.f};
        #pragma unroll
        for (int ni = 0; ni < 4; ++ni)
            #pragma unroll
            for (int j = 0; j < 4; ++j)
                vp[j] += fast_tanh(acc[mi][ni][j] + dpv[ni]) * vv[ni];
        #pragma unroll
        for (int j = 0; j < 4; ++j) {
            float s = vp[j];
            s += __shfl_xor(s, 1); s += __shfl_xor(s, 2);
            s += __shfl_xor(s, 4); s += __shfl_xor(s, 8);
            if (r == 0) {
                int row = wm * 128 + mi * 16 + g * 4 + j;
                atomicAdd(&scores[m0 + row], s);
            }
        }
    }
}

// ---- softmax over T per batch row, in-place ----
__global__ void k_softmax(float* __restrict__ w) {
    int b = blockIdx.x;
    float* row = w + (long)b * TT;
    int tid = threadIdx.x;
    float loc[8];
    float m = -1e30f;
    #pragma unroll
    for (int i = 0; i < 8; ++i) { loc[i] = row[tid + i * 256]; m = fmaxf(m, loc[i]); }
    #pragma unroll
    for (int off = 1; off < 64; off <<= 1) m = fmaxf(m, __shfl_xor(m, off));
    __shared__ float red[4];
    if ((tid & 63) == 0) red[tid >> 6] = m;
    __syncthreads();
    m = fmaxf(fmaxf(red[0], red[1]), fmaxf(red[2], red[3]));
    float s = 0.f;
    #pragma unroll
    for (int i = 0; i < 8; ++i) { loc[i] = __expf(loc[i] - m); s += loc[i]; }
    #pragma unroll
    for (int off = 1; off < 64; off <<= 1) s += __shfl_xor(s, off);
    __shared__ float red2[4];
    if ((tid & 63) == 0) red2[tid >> 6] = s;
    __syncthreads();
    s = red2[0] + red2[1] + red2[2] + red2[3];
    float inv = 1.0f / s;
    #pragma unroll
    for (int i = 0; i < 8; ++i) row[tid + i * 256] = loc[i] * inv;
}

// ---- context from bf16 enc (encb side-product): 4 h/thread ushort4 ----
__global__ void k_context_bf(const unsigned short* __restrict__ encb,
                             const float* __restrict__ w, float* __restrict__ ctx) {
    int bid = blockIdx.x;             // 512 = 32 b x 16 ts
    int b = bid >> 4;
    int ts = bid & 15;
    int h = threadIdx.x * 4;
    const float* wr = w + (long)b * TT + ts * 128;
    long base = ((long)b * TT + (long)ts * 128) * HH + h;
    float a0 = 0.f, a1 = 0.f, a2 = 0.f, a3 = 0.f;
    #pragma unroll 4
    for (int t = 0; t < 128; ++t) {
        ushort4 e = *(const ushort4*)(encb + base + (long)t * HH);
        float ww = wr[t];
        a0 += ww * bf2f(e.x);
        a1 += ww * bf2f(e.y);
        a2 += ww * bf2f(e.z);
        a3 += ww * bf2f(e.w);
    }
    atomicAdd(&ctx[b * HH + h], a0);
    atomicAdd(&ctx[b * HH + h + 1], a1);
    atomicAdd(&ctx[b * HH + h + 2], a2);
    atomicAdd(&ctx[b * HH + h + 3], a3);
}

// ---- fallback context from fp32 enc ----
__global__ void k_context(const float* __restrict__ enc, const float* __restrict__ w,
                          float* __restrict__ ctx) {
    int bid = blockIdx.x;             // 2048 = 32 b x 4 hc x 16 ts
    int b = bid >> 6;
    int hc = (bid >> 4) & 3;
    int ts = bid & 15;
    int h = hc * 256 + threadIdx.x;
    const float* wr = w + (long)b * TT + ts * 128;
    long base = ((long)b * TT + (long)ts * 128) * HH + h;
    float acc = 0.f;
    #pragma unroll 4
    for (int t = 0; t < 128; ++t)
        acc += wr[t] * enc[base + (long)t * HH];
    atomicAdd(&ctx[b * HH + h], acc);
}

extern "C" void kernel_launch(void* const* d_in, const int* in_sizes, int n_in,
                              void* d_out, int out_size, void* d_ws, size_t ws_size,
                              hipStream_t stream) {
    const float* dec  = (const float*)d_in[0];
    const float* enc  = (const float*)d_in[1];
    const float* Wa_w = (const float*)d_in[2];
    const float* Wa_b = (const float*)d_in[3];
    const float* Ua_w = (const float*)d_in[4];
    const float* Ua_b = (const float*)d_in[5];
    const float* v_w  = (const float*)d_in[6];

    float* out  = (float*)d_out;
    float* ctx  = out;                 // [B][H]
    float* attn = out + BB * HH;       // [B][T]

    float* dpw = (float*)d_ws;                                         // 128 KB
    unsigned short* Wb = (unsigned short*)((char*)d_ws + 131072);      // 2 MB
    unsigned short* encb = (unsigned short*)((char*)d_ws + 131072 + 2097152);
    const size_t NEED = 131072ull + 2097152ull + (size_t)BB * TT * HH * 2;

    hipMemsetAsync(d_out, 0, (size_t)out_size * sizeof(float), stream);
    k_convW<<<1024, 256, 0, stream>>>(Wa_w, Wb);
    k_decproj<<<128, 256, 0, stream>>>(dec, Ua_w, Ua_b, Wa_b, dpw);

    if (ws_size >= NEED) {
        k_score_bf<1><<<1024, 512, 0, stream>>>(enc, Wb, dpw, v_w, attn, encb);
        k_softmax<<<BB, 256, 0, stream>>>(attn);
        k_context_bf<<<512, 256, 0, stream>>>(encb, attn, ctx);
    } else {
        k_score_bf<0><<<1024, 512, 0, stream>>>(enc, Wb, dpw, v_w, attn, nullptr);
        k_softmax<<<BB, 256, 0, stream>>>(attn);
        k_context<<<2048, 256, 0, stream>>>(enc, attn, ctx);
    }
}

// Round 25
// 278.381 us; speedup vs baseline: 1.0001x; 1.0001x over previous
//
#include <hip/hip_runtime.h>
#include <hip/hip_bf16.h>

#define HH 1024
#define BB 32
#define TT 2048

typedef __attribute__((ext_vector_type(8))) short bf16x8;
typedef __attribute__((ext_vector_type(4))) float f32x4;

static __device__ __forceinline__ unsigned short f2bf(float f) {
    unsigned int u = __float_as_uint(f);
    unsigned int r = u + 0x7fffu + ((u >> 16) & 1u);
    return (unsigned short)(r >> 16);
}
static __device__ __forceinline__ float bf2f(unsigned short u) {
    return __uint_as_float(((unsigned int)u) << 16);
}
// pack 2 f32 -> 2 bf16 (RNE), single HW instruction
static __device__ __forceinline__ unsigned int cvt_pk_bf16(float lo, float hi) {
    unsigned int d;
    asm volatile("v_cvt_pk_bf16_f32 %0, %1, %2" : "=v"(d) : "v"(lo), "v"(hi));
    return d;
}
// tanh(x) = 1 - 2/(1+e^{2x}); exact at limits, err ~1e-6
static __device__ __forceinline__ float fast_tanh(float x) {
    float e = __expf(2.0f * x);
    return 1.0f - 2.0f / (e + 1.0f);
}

#define GLOAD_LDS16(gp, lp) \
    __builtin_amdgcn_global_load_lds( \
        (const __attribute__((address_space(1))) void*)(gp), \
        (__attribute__((address_space(3))) void*)(lp), 16, 0, 0)

// ---- convert Wa_w (fp32 [H][H]) to bf16 in ws ----
__global__ void k_convW(const float* __restrict__ W, unsigned short* __restrict__ Wb) {
    int i = blockIdx.x * 256 + threadIdx.x;
    float4 v = ((const float4*)W)[i];
    ushort4 o;
    o.x = f2bf(v.x); o.y = f2bf(v.y); o.z = f2bf(v.z); o.w = f2bf(v.w);
    ((ushort4*)Wb)[i] = o;
}

// ---- dec_proj[b][o] = dot(dec[b,:], Ua_w[o,:]) + Ua_b[o] + Wa_b[o] ----
__global__ void k_decproj(const float* __restrict__ dec, const float* __restrict__ Ua,
                          const float* __restrict__ Uab, const float* __restrict__ Wab,
                          float* __restrict__ dp) {
    int gtid = blockIdx.x * 256 + threadIdx.x;   // 32768
    int b = gtid >> 10, o = gtid & 1023;
    const float4* d4 = (const float4*)(dec + (long)b * HH);
    const float4* u4 = (const float4*)(Ua + (long)o * HH);
    float acc = 0.f;
    for (int k = 0; k < HH / 4; ++k) {
        float4 a = d4[k], w = u4[k];
        acc += a.x * w.x + a.y * w.y + a.z * w.z + a.w * w.w;
    }
    dp[gtid] = acc + Uab[o] + Wab[o];
}

// === FAST PATH: r23 pipeline + encb side-product, store-transparent vmcnt ===
// A (fp32 enc): tile-deep reg-staged pipeline (r23). cvt results stream to
// encb (block nt stores k-tiles with k&3==nt). Queue at tile-end vmcnt:
// B(4) -> stores(0|4) -> A(8); drain ONLY B => vmcnt(12) on store-tiles,
// vmcnt(8) otherwise (block-uniform branch). Stores are never waited
// mid-loop; kernel-end retirement orders them before k_context_bf.
template<int WRITE_ENC>
__global__ __launch_bounds__(512) void k_score_bf(
        const float* __restrict__ enc, const unsigned short* __restrict__ Wb,
        const float* __restrict__ dp, const float* __restrict__ vw,
        float* __restrict__ scores, unsigned short* __restrict__ encb) {
    __shared__ __align__(16) unsigned short As[2][256 * 64];
    __shared__ __align__(16) unsigned short Bs[2][256 * 64];
    int bid = blockIdx.x;            // 1024 blocks = 256 mt x 4 nt
    int xcd = bid & 7;
    int ord = bid >> 3;              // 0..127 per XCD
    int nt = ord & 3;                // XCD walks nt 0..3 (A-panel L2-reuse)
    int mt = (ord >> 2) * 8 + xcd;   // 0..255
    long m0 = (long)mt * 256;
    int o0b = nt * 256;
    int tid = threadIdx.x;
    int lane = tid & 63, wid = tid >> 6;      // 8 waves
    int wm = wid >> 2, wn = wid & 3;          // 2 x 4; wave tile 128r x 64c
    int r = lane & 15, g = lane >> 4;

    f32x4 acc[8][4];
    #pragma unroll
    for (int i = 0; i < 8; ++i)
        #pragma unroll
        for (int j = 0; j < 4; ++j) acc[i][j] = (f32x4){0.f, 0.f, 0.f, 0.f};

    int srow = tid >> 3;
    int acol = (tid & 7) * 8;
    int awu = (tid & 7) ^ (srow & 7);
    const float* aSrcF = enc + (m0 + srow) * HH + acol;
    const unsigned short* bSrc = Wb + (long)(o0b + srow) * HH + awu * 8;
    unsigned short* eDst = WRITE_ENC ? encb + (m0 + srow) * HH + acol : nullptr;
    int ldso = wid * 512;
    int rx = r & 7;
    int u0 = (g ^ rx) * 8;
    int u1 = ((4 + g) ^ rx) * 8;
    int aw0 = srow * 64 + awu * 8;   // + q*4096 per pass (shorts)

    float4 ar[8];                    // A prefetch regs (one tile in flight)

    // prologue: A(0) direct (load+cvt+write[+store]), B(0) gloads, A(1) issued
    {
        float4 a0[8];
        #pragma unroll
        for (int q = 0; q < 4; ++q) {
            a0[2 * q]     = *(const float4*)(aSrcF + (long)64 * q * HH);
            a0[2 * q + 1] = *(const float4*)(aSrcF + (long)64 * q * HH + 4);
            GLOAD_LDS16(bSrc + (long)q * 64 * HH, &Bs[0][ldso + q * 4096]);
        }
        uint4 wv[4];
        #pragma unroll
        for (int q = 0; q < 4; ++q) {
            wv[q].x = cvt_pk_bf16(a0[2 * q].x, a0[2 * q].y);
            wv[q].y = cvt_pk_bf16(a0[2 * q].z, a0[2 * q].w);
            wv[q].z = cvt_pk_bf16(a0[2 * q + 1].x, a0[2 * q + 1].y);
            wv[q].w = cvt_pk_bf16(a0[2 * q + 1].z, a0[2 * q + 1].w);
            *(uint4*)(&As[0][aw0 + q * 4096]) = wv[q];
        }
        if (WRITE_ENC && nt == 0) {          // store k-tile 0
            #pragma unroll
            for (int q = 0; q < 4; ++q)
                *(uint4*)(eDst + (long)64 * q * HH) = wv[q];
        }
        #pragma unroll
        for (int q = 0; q < 4; ++q) {        // A(1): in flight across barrier
            ar[2 * q]     = *(const float4*)(aSrcF + (long)64 * q * HH + 64);
            ar[2 * q + 1] = *(const float4*)(aSrcF + (long)64 * q * HH + 64 + 4);
        }
        // queue: B(4) [a0 drained by cvt dep] -> stores(0|4) -> A(8)
        if (WRITE_ENC && nt == 0)
            asm volatile("s_waitcnt vmcnt(12)" ::: "memory");  // drain B only
        else
            asm volatile("s_waitcnt vmcnt(8)" ::: "memory");   // drain B only
        asm volatile("s_waitcnt lgkmcnt(0)" ::: "memory");     // A(0) writes done
        __builtin_amdgcn_s_barrier();
        __builtin_amdgcn_sched_barrier(0);
    }

    #pragma unroll 1
    for (int t = 0; t < 16; ++t) {
        int bi = t & 1, pi = bi ^ 1;
        int kc2 = (t + 1) * 64;
        bool pre = (t < 15);

        // B fragments for the whole tile
        bf16x8 bfr[4][2];
        #pragma unroll
        for (int ni = 0; ni < 4; ++ni) {
            int rowb = (wn * 64 + ni * 16 + r) * 64;
            bfr[ni][0] = *(const bf16x8*)(&Bs[bi][rowb + u0]);
            bfr[ni][1] = *(const bf16x8*)(&Bs[bi][rowb + u1]);
        }
        // quad 0 A reads (mi = 0,1)
        bf16x8 aq[2][2][2];
        #pragma unroll
        for (int q = 0; q < 2; ++q) {
            int rowa = (wm * 128 + q * 16 + r) * 64;
            aq[0][q][0] = *(const bf16x8*)(&As[bi][rowa + u0]);
            aq[0][q][1] = *(const bf16x8*)(&As[bi][rowa + u1]);
        }

        #pragma unroll
        for (int p = 0; p < 4; ++p) {
            if (pre && p == 0) {
                GLOAD_LDS16(bSrc + kc2 + (long)0 * 64 * HH, &Bs[pi][ldso + 0 * 4096]);
                GLOAD_LDS16(bSrc + kc2 + (long)1 * 64 * HH, &Bs[pi][ldso + 1 * 4096]);
            }
            if (pre && p == 1) {
                GLOAD_LDS16(bSrc + kc2 + (long)2 * 64 * HH, &Bs[pi][ldso + 2 * 4096]);
                GLOAD_LDS16(bSrc + kc2 + (long)3 * 64 * HH, &Bs[pi][ldso + 3 * 4096]);
            }
            if (p < 3) {
                #pragma unroll
                for (int q = 0; q < 2; ++q) {
                    int rowa = (wm * 128 + (2 * (p + 1) + q) * 16 + r) * 64;
                    aq[(p + 1) & 1][q][0] = *(const bf16x8*)(&As[bi][rowa + u0]);
                    aq[(p + 1) & 1][q][1] = *(const bf16x8*)(&As[bi][rowa + u1]);
                }
            }
            __builtin_amdgcn_s_setprio(1);
            #pragma unroll
            for (int q = 0; q < 2; ++q) {
                int mi = 2 * p + q;
                #pragma unroll
                for (int ni = 0; ni < 4; ++ni) {
                    acc[mi][ni] = __builtin_amdgcn_mfma_f32_16x16x32_bf16(
                        aq[p & 1][q][0], bfr[ni][0], acc[mi][ni], 0, 0, 0);
                    acc[mi][ni] = __builtin_amdgcn_mfma_f32_16x16x32_bf16(
                        aq[p & 1][q][1], bfr[ni][1], acc[mi][ni], 0, 0, 0);
                }
            }
            __builtin_amdgcn_s_setprio(0);
        }

        // tile end: convert A(t+1), LDS-write, (balanced) stream to encb
        bool storeTile = WRITE_ENC && pre && (((t + 1) & 3) == nt);
        if (pre) {
            uint4 wv[4];
            #pragma unroll
            for (int q = 0; q < 4; ++q) {
                wv[q].x = cvt_pk_bf16(ar[2 * q].x, ar[2 * q].y);
                wv[q].y = cvt_pk_bf16(ar[2 * q].z, ar[2 * q].w);
                wv[q].z = cvt_pk_bf16(ar[2 * q + 1].x, ar[2 * q + 1].y);
                wv[q].w = cvt_pk_bf16(ar[2 * q + 1].z, ar[2 * q + 1].w);
                *(uint4*)(&As[pi][aw0 + q * 4096]) = wv[q];
            }
            if (storeTile) {                          // store k-tile t+1
                #pragma unroll
                for (int q = 0; q < 4; ++q)
                    *(uint4*)(eDst + (long)64 * q * HH + kc2) = wv[q];
            }
        }
        if (t < 14) {
            int kc3 = (t + 2) * 64;             // A(t+2): issue BEFORE barrier
            #pragma unroll
            for (int q = 0; q < 4; ++q) {
                ar[2 * q]     = *(const float4*)(aSrcF + (long)64 * q * HH + kc3);
                ar[2 * q + 1] = *(const float4*)(aSrcF + (long)64 * q * HH + kc3 + 4);
            }
            // queue: B(4) -> stores(0|4) -> A(8); drain ONLY B
            if (storeTile)
                asm volatile("s_waitcnt vmcnt(12)" ::: "memory");
            else
                asm volatile("s_waitcnt vmcnt(8)" ::: "memory");
        } else if (t == 14) {
            asm volatile("s_waitcnt vmcnt(0)" ::: "memory");   // B(15)+stores
        }
        if (pre) {
            asm volatile("s_waitcnt lgkmcnt(0)" ::: "memory"); // A writes done
            __builtin_amdgcn_s_barrier();
            __builtin_amdgcn_sched_barrier(0);
        }
    }

    // epilogue: scores[m] += sum_o tanh(acc + dp[b][o]) * v[o]
    int bb = (int)(m0 >> 11);        // 256 | 2048 -> single batch per tile
    float vv[4], dpv[4];
    #pragma unroll
    for (int ni = 0; ni < 4; ++ni) {
        int o = o0b + wn * 64 + ni * 16 + r;
        vv[ni] = vw[o];
        dpv[ni] = dp[bb * HH + o];
    }
    #pragma unroll
    for (int mi = 0; mi < 8; ++mi) {
        float vp[4] = {0.f, 0.f, 0.f, 0.f};
        #pragma unroll
        for (int ni = 0; ni < 4; ++ni)
            #pragma unroll
            for (int j = 0; j < 4; ++j)
                vp[j] += fast_tanh(acc[mi][ni][j] + dpv[ni]) * vv[ni];
        #pragma unroll
        for (int j = 0; j < 4; ++j) {
            float s = vp[j];
            s += __shfl_xor(s, 1); s += __shfl_xor(s, 2);
            s += __shfl_xor(s, 4); s += __shfl_xor(s, 8);
            if (r == 0) {
                int row = wm * 128 + mi * 16 + g * 4 + j;
                atomicAdd(&scores[m0 + row], s);
            }
        }
    }
}

// ---- softmax over T per batch row, in-place ----
__global__ void k_softmax(float* __restrict__ w) {
    int b = blockIdx.x;
    float* row = w + (long)b * TT;
    int tid = threadIdx.x;
    float loc[8];
    float m = -1e30f;
    #pragma unroll
    for (int i = 0; i < 8; ++i) { loc[i] = row[tid + i * 256]; m = fmaxf(m, loc[i]); }
    #pragma unroll
    for (int off = 1; off < 64; off <<= 1) m = fmaxf(m, __shfl_xor(m, off));
    __shared__ float red[4];
    if ((tid & 63) == 0) red[tid >> 6] = m;
    __syncthreads();
    m = fmaxf(fmaxf(red[0], red[1]), fmaxf(red[2], red[3]));
    float s = 0.f;
    #pragma unroll
    for (int i = 0; i < 8; ++i) { loc[i] = __expf(loc[i] - m); s += loc[i]; }
    #pragma unroll
    for (int off = 1; off < 64; off <<= 1) s += __shfl_xor(s, off);
    __shared__ float red2[4];
    if ((tid & 63) == 0) red2[tid >> 6] = s;
    __syncthreads();
    s = red2[0] + red2[1] + red2[2] + red2[3];
    float inv = 1.0f / s;
    #pragma unroll
    for (int i = 0; i < 8; ++i) row[tid + i * 256] = loc[i] * inv;
}

// ---- context from bf16 enc (encb side-product): 4 h/thread ushort4 ----
__global__ void k_context_bf(const unsigned short* __restrict__ encb,
                             const float* __restrict__ w, float* __restrict__ ctx) {
    int bid = blockIdx.x;             // 512 = 32 b x 16 ts
    int b = bid >> 4;
    int ts = bid & 15;
    int h = threadIdx.x * 4;
    const float* wr = w + (long)b * TT + ts * 128;
    long base = ((long)b * TT + (long)ts * 128) * HH + h;
    float a0 = 0.f, a1 = 0.f, a2 = 0.f, a3 = 0.f;
    #pragma unroll 4
    for (int t = 0; t < 128; ++t) {
        ushort4 e = *(const ushort4*)(encb + base + (long)t * HH);
        float ww = wr[t];
        a0 += ww * bf2f(e.x);
        a1 += ww * bf2f(e.y);
        a2 += ww * bf2f(e.z);
        a3 += ww * bf2f(e.w);
    }
    atomicAdd(&ctx[b * HH + h], a0);
    atomicAdd(&ctx[b * HH + h + 1], a1);
    atomicAdd(&ctx[b * HH + h + 2], a2);
    atomicAdd(&ctx[b * HH + h + 3], a3);
}

// ---- fallback context from fp32 enc ----
__global__ void k_context(const float* __restrict__ enc, const float* __restrict__ w,
                          float* __restrict__ ctx) {
    int bid = blockIdx.x;             // 2048 = 32 b x 4 hc x 16 ts
    int b = bid >> 6;
    int hc = (bid >> 4) & 3;
    int ts = bid & 15;
    int h = hc * 256 + threadIdx.x;
    const float* wr = w + (long)b * TT + ts * 128;
    long base = ((long)b * TT + (long)ts * 128) * HH + h;
    float acc = 0.f;
    #pragma unroll 4
    for (int t = 0; t < 128; ++t)
        acc += wr[t] * enc[base + (long)t * HH];
    atomicAdd(&ctx[b * HH + h], acc);
}

extern "C" void kernel_launch(void* const* d_in, const int* in_sizes, int n_in,
                              void* d_out, int out_size, void* d_ws, size_t ws_size,
                              hipStream_t stream) {
    const float* dec  = (const float*)d_in[0];
    const float* enc  = (const float*)d_in[1];
    const float* Wa_w = (const float*)d_in[2];
    const float* Wa_b = (const float*)d_in[3];
    const float* Ua_w = (const float*)d_in[4];
    const float* Ua_b = (const float*)d_in[5];
    const float* v_w  = (const float*)d_in[6];

    float* out  = (float*)d_out;
    float* ctx  = out;                 // [B][H]
    float* attn = out + BB * HH;       // [B][T]

    float* dpw = (float*)d_ws;                                         // 128 KB
    unsigned short* Wb = (unsigned short*)((char*)d_ws + 131072);      // 2 MB
    unsigned short* encb = (unsigned short*)((char*)d_ws + 131072 + 2097152);
    const size_t NEED = 131072ull + 2097152ull + (size_t)BB * TT * HH * 2;

    hipMemsetAsync(d_out, 0, (size_t)out_size * sizeof(float), stream);
    k_convW<<<1024, 256, 0, stream>>>(Wa_w, Wb);
    k_decproj<<<128, 256, 0, stream>>>(dec, Ua_w, Ua_b, Wa_b, dpw);

    if (ws_size >= NEED) {
        k_score_bf<1><<<1024, 512, 0, stream>>>(enc, Wb, dpw, v_w, attn, encb);
        k_softmax<<<BB, 256, 0, stream>>>(attn);
        k_context_bf<<<512, 256, 0, stream>>>(encb, attn, ctx);
    } else {
        k_score_bf<0><<<1024, 512, 0, stream>>>(enc, Wb, dpw, v_w, attn, nullptr);
        k_softmax<<<BB, 256, 0, stream>>>(attn);
        k_context<<<2048, 256, 0, stream>>>(enc, attn, ctx);
    }
}

// Round 26
// 261.585 us; speedup vs baseline: 1.0643x; 1.0642x over previous
//
#include <hip/hip_runtime.h>
#include <hip/hip_bf16.h>

#define HH 1024
#define BB 32
#define TT 2048

typedef __attribute__((ext_vector_type(8))) short bf16x8;
typedef __attribute__((ext_vector_type(4))) float f32x4;

static __device__ __forceinline__ unsigned short f2bf(float f) {
    unsigned int u = __float_as_uint(f);
    unsigned int r = u + 0x7fffu + ((u >> 16) & 1u);
    return (unsigned short)(r >> 16);
}
// pack 2 f32 -> 2 bf16 (RNE), single HW instruction
static __device__ __forceinline__ unsigned int cvt_pk_bf16(float lo, float hi) {
    unsigned int d;
    asm volatile("v_cvt_pk_bf16_f32 %0, %1, %2" : "=v"(d) : "v"(lo), "v"(hi));
    return d;
}
// tanh(x) = 1 - 2/(1+e^{2x}); exact at limits, err ~1e-6
static __device__ __forceinline__ float fast_tanh(float x) {
    float e = __expf(2.0f * x);
    return 1.0f - 2.0f / (e + 1.0f);
}

#define GLOAD_LDS16(gp, lp) \
    __builtin_amdgcn_global_load_lds( \
        (const __attribute__((address_space(1))) void*)(gp), \
        (__attribute__((address_space(3))) void*)(lp), 16, 0, 0)

// ---- convert Wa_w (fp32 [H][H]) to bf16 in ws ----
__global__ void k_convW(const float* __restrict__ W, unsigned short* __restrict__ Wb) {
    int i = blockIdx.x * 256 + threadIdx.x;
    float4 v = ((const float4*)W)[i];
    ushort4 o;
    o.x = f2bf(v.x); o.y = f2bf(v.y); o.z = f2bf(v.z); o.w = f2bf(v.w);
    ((ushort4*)Wb)[i] = o;
}

// ---- dec_proj[b][o] = dot(dec[b,:], Ua_w[o,:]) + Ua_b[o] + Wa_b[o] ----
__global__ void k_decproj(const float* __restrict__ dec, const float* __restrict__ Ua,
                          const float* __restrict__ Uab, const float* __restrict__ Wab,
                          float* __restrict__ dp) {
    int gtid = blockIdx.x * 256 + threadIdx.x;   // 32768
    int b = gtid >> 10, o = gtid & 1023;
    const float4* d4 = (const float4*)(dec + (long)b * HH);
    const float4* u4 = (const float4*)(Ua + (long)o * HH);
    float acc = 0.f;
    for (int k = 0; k < HH / 4; ++k) {
        float4 a = d4[k], w = u4[k];
        acc += a.x * w.x + a.y * w.y + a.z * w.z + a.w * w.w;
    }
    dp[gtid] = acc + Uab[o] + Wab[o];
}

// === FAST PATH: 256x256, 8 waves, r13 skeleton + tile-deep A prefetch ===
// (round-23 kernel, measured best: score 211us, total 262.9us)
// A (fp32 enc): reg-staged with ONE-TILE-DEEP pipeline -- A(t+1)'s 8 float4
// issue at tile t-1's END, convert (v_cvt_pk_bf16_f32) + swizzled ds_write
// at tile t's end, then A(t+2) issues into the freed regs BEFORE the
// barrier. Barrier = counted vmcnt(8) (waits only B's gloads; A loads fly
// across it) + lgkmcnt(0) + raw s_barrier. B: gload_lds as r13.
__global__ __launch_bounds__(512) void k_score_bf(
        const float* __restrict__ enc, const unsigned short* __restrict__ Wb,
        const float* __restrict__ dp, const float* __restrict__ vw,
        float* __restrict__ scores) {
    __shared__ __align__(16) unsigned short As[2][256 * 64];
    __shared__ __align__(16) unsigned short Bs[2][256 * 64];
    int bid = blockIdx.x;            // 1024 blocks = 256 mt x 4 nt
    int xcd = bid & 7;
    int ord = bid >> 3;              // 0..127 per XCD
    int nt = ord & 3;                // XCD walks nt 0..3 (A-panel L2-reuse)
    int mt = (ord >> 2) * 8 + xcd;   // 0..255
    long m0 = (long)mt * 256;
    int o0b = nt * 256;
    int tid = threadIdx.x;
    int lane = tid & 63, wid = tid >> 6;      // 8 waves
    int wm = wid >> 2, wn = wid & 3;          // 2 x 4; wave tile 128r x 64c
    int r = lane & 15, g = lane >> 4;

    f32x4 acc[8][4];
    #pragma unroll
    for (int i = 0; i < 8; ++i)
        #pragma unroll
        for (int j = 0; j < 4; ++j) acc[i][j] = (f32x4){0.f, 0.f, 0.f, 0.f};

    // staging maps. A: thread owns rows srow+64q, 8 floats at col
    // (tid&7)*8; writes bf16x8 to LDS unit (tid&7)^(srow&7). B: gload_lds
    // with pre-swizzled global unit.
    int srow = tid >> 3;
    int acol = (tid & 7) * 8;
    int awu = (tid & 7) ^ (srow & 7);
    const float* aSrcF = enc + (m0 + srow) * HH + acol;
    const unsigned short* bSrc = Wb + (long)(o0b + srow) * HH + awu * 8;
    int ldso = wid * 512;
    int rx = r & 7;
    int u0 = (g ^ rx) * 8;
    int u1 = ((4 + g) ^ rx) * 8;
    int aw0 = srow * 64 + awu * 8;   // + q*4096 per pass (shorts)

    float4 ar[8];                    // A prefetch regs (one tile in flight)

    // prologue: A(0) direct (load+cvt+write), B(0) gloads, A(1) issued
    {
        float4 a0[8];
        #pragma unroll
        for (int q = 0; q < 4; ++q) {
            a0[2 * q]     = *(const float4*)(aSrcF + (long)64 * q * HH);
            a0[2 * q + 1] = *(const float4*)(aSrcF + (long)64 * q * HH + 4);
            GLOAD_LDS16(bSrc + (long)q * 64 * HH, &Bs[0][ldso + q * 4096]);
        }
        #pragma unroll
        for (int q = 0; q < 4; ++q) {
            uint4 w;
            w.x = cvt_pk_bf16(a0[2 * q].x, a0[2 * q].y);
            w.y = cvt_pk_bf16(a0[2 * q].z, a0[2 * q].w);
            w.z = cvt_pk_bf16(a0[2 * q + 1].x, a0[2 * q + 1].y);
            w.w = cvt_pk_bf16(a0[2 * q + 1].z, a0[2 * q + 1].w);
            *(uint4*)(&As[0][aw0 + q * 4096]) = w;
        }
        #pragma unroll
        for (int q = 0; q < 4; ++q) {          // A(1): in flight across barrier
            ar[2 * q]     = *(const float4*)(aSrcF + (long)64 * q * HH + 64);
            ar[2 * q + 1] = *(const float4*)(aSrcF + (long)64 * q * HH + 64 + 4);
        }
        asm volatile("s_waitcnt vmcnt(8)" ::: "memory");   // B(0) done
        asm volatile("s_waitcnt lgkmcnt(0)" ::: "memory"); // A(0) writes done
        __builtin_amdgcn_s_barrier();
        __builtin_amdgcn_sched_barrier(0);
    }

    #pragma unroll 1
    for (int t = 0; t < 16; ++t) {
        int bi = t & 1, pi = bi ^ 1;
        int kc2 = (t + 1) * 64;
        bool pre = (t < 15);

        // B fragments for the whole tile
        bf16x8 bfr[4][2];
        #pragma unroll
        for (int ni = 0; ni < 4; ++ni) {
            int rowb = (wn * 64 + ni * 16 + r) * 64;
            bfr[ni][0] = *(const bf16x8*)(&Bs[bi][rowb + u0]);
            bfr[ni][1] = *(const bf16x8*)(&Bs[bi][rowb + u1]);
        }
        // quad 0 A reads (mi = 0,1)
        bf16x8 aq[2][2][2];
        #pragma unroll
        for (int q = 0; q < 2; ++q) {
            int rowa = (wm * 128 + q * 16 + r) * 64;
            aq[0][q][0] = *(const bf16x8*)(&As[bi][rowa + u0]);
            aq[0][q][1] = *(const bf16x8*)(&As[bi][rowa + u1]);
        }

        #pragma unroll
        for (int p = 0; p < 4; ++p) {
            if (pre && p == 0) {
                GLOAD_LDS16(bSrc + kc2 + (long)0 * 64 * HH, &Bs[pi][ldso + 0 * 4096]);
                GLOAD_LDS16(bSrc + kc2 + (long)1 * 64 * HH, &Bs[pi][ldso + 1 * 4096]);
            }
            if (pre && p == 1) {
                GLOAD_LDS16(bSrc + kc2 + (long)2 * 64 * HH, &Bs[pi][ldso + 2 * 4096]);
                GLOAD_LDS16(bSrc + kc2 + (long)3 * 64 * HH, &Bs[pi][ldso + 3 * 4096]);
            }
            if (p < 3) {
                #pragma unroll
                for (int q = 0; q < 2; ++q) {
                    int rowa = (wm * 128 + (2 * (p + 1) + q) * 16 + r) * 64;
                    aq[(p + 1) & 1][q][0] = *(const bf16x8*)(&As[bi][rowa + u0]);
                    aq[(p + 1) & 1][q][1] = *(const bf16x8*)(&As[bi][rowa + u1]);
                }
            }
            __builtin_amdgcn_s_setprio(1);
            #pragma unroll
            for (int q = 0; q < 2; ++q) {
                int mi = 2 * p + q;
                #pragma unroll
                for (int ni = 0; ni < 4; ++ni) {
                    acc[mi][ni] = __builtin_amdgcn_mfma_f32_16x16x32_bf16(
                        aq[p & 1][q][0], bfr[ni][0], acc[mi][ni], 0, 0, 0);
                    acc[mi][ni] = __builtin_amdgcn_mfma_f32_16x16x32_bf16(
                        aq[p & 1][q][1], bfr[ni][1], acc[mi][ni], 0, 0, 0);
                }
            }
            __builtin_amdgcn_s_setprio(0);
        }

        // tile end: convert A(t+1) (loaded one tile ago; cvt's reg use
        // makes the compiler wait vmcnt(4) -- only B still outstanding)
        if (pre) {
            #pragma unroll
            for (int q = 0; q < 4; ++q) {
                uint4 w;
                w.x = cvt_pk_bf16(ar[2 * q].x, ar[2 * q].y);
                w.y = cvt_pk_bf16(ar[2 * q].z, ar[2 * q].w);
                w.z = cvt_pk_bf16(ar[2 * q + 1].x, ar[2 * q + 1].y);
                w.w = cvt_pk_bf16(ar[2 * q + 1].z, ar[2 * q + 1].w);
                *(uint4*)(&As[pi][aw0 + q * 4096]) = w;
            }
        }
        if (t < 14) {
            int kc3 = (t + 2) * 64;             // A(t+2): issue BEFORE barrier
            #pragma unroll
            for (int q = 0; q < 4; ++q) {
                ar[2 * q]     = *(const float4*)(aSrcF + (long)64 * q * HH + kc3);
                ar[2 * q + 1] = *(const float4*)(aSrcF + (long)64 * q * HH + kc3 + 4);
            }
            asm volatile("s_waitcnt vmcnt(8)" ::: "memory");   // B(t+1) done
        } else if (t == 14) {
            asm volatile("s_waitcnt vmcnt(0)" ::: "memory");   // B(15) done
        }
        if (pre) {
            asm volatile("s_waitcnt lgkmcnt(0)" ::: "memory"); // A writes done
            __builtin_amdgcn_s_barrier();
            __builtin_amdgcn_sched_barrier(0);
        }
    }

    // epilogue: scores[m] += sum_o tanh(acc + dp[b][o]) * v[o]
    int bb = (int)(m0 >> 11);        // 256 | 2048 -> single batch per tile
    float vv[4], dpv[4];
    #pragma unroll
    for (int ni = 0; ni < 4; ++ni) {
        int o = o0b + wn * 64 + ni * 16 + r;
        vv[ni] = vw[o];
        dpv[ni] = dp[bb * HH + o];
    }
    #pragma unroll
    for (int mi = 0; mi < 8; ++mi) {
        float vp[4] = {0.f, 0.f, 0.f, 0.f};
        #pragma unroll
        for (int ni = 0; ni < 4; ++ni)
            #pragma unroll
            for (int j = 0; j < 4; ++j)
                vp[j] += fast_tanh(acc[mi][ni][j] + dpv[ni]) * vv[ni];
        #pragma unroll
        for (int j = 0; j < 4; ++j) {
            float s = vp[j];
            s += __shfl_xor(s, 1); s += __shfl_xor(s, 2);
            s += __shfl_xor(s, 4); s += __shfl_xor(s, 8);
            if (r == 0) {
                int row = wm * 128 + mi * 16 + g * 4 + j;
                atomicAdd(&scores[m0 + row], s);
            }
        }
    }
}

// ---- softmax over T per batch row, in-place ----
__global__ void k_softmax(float* __restrict__ w) {
    int b = blockIdx.x;
    float* row = w + (long)b * TT;
    int tid = threadIdx.x;
    float loc[8];
    float m = -1e30f;
    #pragma unroll
    for (int i = 0; i < 8; ++i) { loc[i] = row[tid + i * 256]; m = fmaxf(m, loc[i]); }
    #pragma unroll
    for (int off = 1; off < 64; off <<= 1) m = fmaxf(m, __shfl_xor(m, off));
    __shared__ float red[4];
    if ((tid & 63) == 0) red[tid >> 6] = m;
    __syncthreads();
    m = fmaxf(fmaxf(red[0], red[1]), fmaxf(red[2], red[3]));
    float s = 0.f;
    #pragma unroll
    for (int i = 0; i < 8; ++i) { loc[i] = __expf(loc[i] - m); s += loc[i]; }
    #pragma unroll
    for (int off = 1; off < 64; off <<= 1) s += __shfl_xor(s, off);
    __shared__ float red2[4];
    if ((tid & 63) == 0) red2[tid >> 6] = s;
    __syncthreads();
    s = red2[0] + red2[1] + red2[2] + red2[3];
    float inv = 1.0f / s;
    #pragma unroll
    for (int i = 0; i < 8; ++i) row[tid + i * 256] = loc[i] * inv;
}

// ---- context from fp32 enc: coalesced, 16-way atomics ----
__global__ void k_context(const float* __restrict__ enc, const float* __restrict__ w,
                          float* __restrict__ ctx) {
    int bid = blockIdx.x;             // 2048 = 32 b x 4 hc x 16 ts
    int b = bid >> 6;
    int hc = (bid >> 4) & 3;
    int ts = bid & 15;
    int h = hc * 256 + threadIdx.x;
    const float* wr = w + (long)b * TT + ts * 128;
    long base = ((long)b * TT + (long)ts * 128) * HH + h;
    float acc = 0.f;
    #pragma unroll 4
    for (int t = 0; t < 128; ++t)
        acc += wr[t] * enc[base + (long)t * HH];
    atomicAdd(&ctx[b * HH + h], acc);
}

extern "C" void kernel_launch(void* const* d_in, const int* in_sizes, int n_in,
                              void* d_out, int out_size, void* d_ws, size_t ws_size,
                              hipStream_t stream) {
    const float* dec  = (const float*)d_in[0];
    const float* enc  = (const float*)d_in[1];
    const float* Wa_w = (const float*)d_in[2];
    const float* Wa_b = (const float*)d_in[3];
    const float* Ua_w = (const float*)d_in[4];
    const float* Ua_b = (const float*)d_in[5];
    const float* v_w  = (const float*)d_in[6];

    float* out  = (float*)d_out;
    float* ctx  = out;                 // [B][H]
    float* attn = out + BB * HH;       // [B][T]

    float* dpw = (float*)d_ws;                                    // 128 KB
    unsigned short* Wb = (unsigned short*)((char*)d_ws + 131072); // 2 MB

    hipMemsetAsync(d_out, 0, (size_t)out_size * sizeof(float), stream);
    k_convW<<<1024, 256, 0, stream>>>(Wa_w, Wb);
    k_decproj<<<128, 256, 0, stream>>>(dec, Ua_w, Ua_b, Wa_b, dpw);
    k_score_bf<<<1024, 512, 0, stream>>>(enc, Wb, dpw, v_w, attn);
    k_softmax<<<BB, 256, 0, stream>>>(attn);
    k_context<<<2048, 256, 0, stream>>>(enc, attn, ctx);
}